// Round 1
// baseline (688.068 us; speedup 1.0000x reference)
//
#include <hip/hip_runtime.h>
#include <math.h>

// Problem constants
#define NH   7        // hazards
#define NROW 16384    // B*S = 8*2048
#define DD   768      // hidden dim
#define KK   64       // bottleneck dim
#define THRG 0.05f

typedef float  f32x4   __attribute__((ext_vector_type(4)));
typedef __bf16 bf16x8  __attribute__((ext_vector_type(8)));
typedef short  short8v __attribute__((ext_vector_type(8)));
typedef short  short4v __attribute__((ext_vector_type(4)));

union V8 { short8v s; bf16x8 b; };

__device__ __forceinline__ unsigned short f2bf(float f) {
  unsigned u = __float_as_uint(f);
  u = (u + 0x7FFFu + ((u >> 16) & 1u)) >> 16;   // round-to-nearest-even
  return (unsigned short)u;
}

__device__ __forceinline__ float gate_of(const float* __restrict__ M, int s, int t) {
  float m = M[s * NH + t];
  return (s != t && fabsf(m) > THRG) ? m : 0.0f;
}

__device__ __forceinline__ float gelu_t(float v) {
  float u = 0.7978845608028654f * (v + 0.044715f * v * v * v);
  return v / (1.0f + __expf(-2.0f * u));   // v * sigmoid(2u)
}

// async 16B global -> LDS copy (dest = wave-uniform base + lane*16)
__device__ __forceinline__ void gload_lds16(const void* g, void* l) {
  __builtin_amdgcn_global_load_lds(
      (const __attribute__((address_space(1))) unsigned int*)g,
      (__attribute__((address_space(3))) unsigned int*)l, 16, 0, 0);
}

// ---- prep: W1 [s][t][d][k] f32 -> W1P [pr][kc][kcol(64)][dl(64)] bf16,
// PRE-SWIZZLED (inverse of the LDS read XOR) so global_load_lds can copy linearly.
__global__ void prep_w1(const float* __restrict__ W1, unsigned short* __restrict__ W1P) {
  int pr = blockIdx.x;                       // pr = s*7+t
  const float* src = W1 + (size_t)pr * DD * KK;
  unsigned short* dst = W1P + (size_t)pr * 12 * 4096;
  for (int idx = threadIdx.x; idx < 12 * 4096; idx += blockDim.x) {
    int kc = idx >> 12, rem = idx & 4095;
    int kcol = rem >> 6, dl = rem & 63;
    int dl_log = dl ^ ((kcol & 7) << 3);     // elem-space inverse of byte XOR ((row&7)<<4)
    dst[idx] = f2bf(src[(size_t)(kc * 64 + dl_log) * KK + kcol]);
  }
}

// ---- prep: W2 [s][t][k][d] f32 -> W2P [t][s][d(768)][k(64)] bf16, gate folded.
// Read directly from global (L2-hot) as MFMA A-fragments; no swizzle needed.
__global__ void prep_w2(const float* __restrict__ M, const float* __restrict__ W2,
                        unsigned short* __restrict__ W2P) {
  int st = blockIdx.x;                       // st = s*7+t
  int s = st / NH, t = st % NH;
  float g = gate_of(M, s, t);
  const float* src = W2 + (size_t)st * KK * DD;
  unsigned short* dst = W2P + (size_t)(t * NH + s) * DD * KK;
  for (int idx = threadIdx.x; idx < DD * KK; idx += blockDim.x) {
    int d = idx >> 6, k = idx & 63;
    dst[idx] = f2bf(g * src[(size_t)k * DD + d]);
  }
}

// ---- prep: b2sum[t][d] = sum_s gate(s,t) * b2[s][t][d]
__global__ void prep_b2(const float* __restrict__ M, const float* __restrict__ b2,
                        float* __restrict__ b2sum) {
  int idx = blockIdx.x * blockDim.x + threadIdx.x;
  if (idx >= NH * DD) return;
  int t = idx / DD, d = idx % DD;
  float acc = 0.f;
  for (int s = 0; s < NH; ++s)
    acc += gate_of(M, s, t) * b2[(size_t)(s * NH + t) * DD + d];
  b2sum[idx] = acc;
}

// ---- Fused kernel: per (target t, 128-row block):
//   Phase A: for each active source s: H[s] = gelu(x[s]·W1[s,t] + b1) -> LDS (bf16)
//   Phase B: out[t] = x[t] + sum_s H[s]·(gate·W2[s,t]) + b2sum[t]
// H never touches HBM. 512 threads = 8 waves; LDS = 96K (H) + 32K (x dbuf) + 16K (W1 dbuf).
__global__ __launch_bounds__(512, 2)
void chiF(const float* __restrict__ x, const float* __restrict__ M,
          const unsigned short* __restrict__ W1P, const float* __restrict__ b1,
          const unsigned short* __restrict__ W2P, const float* __restrict__ b2sum,
          float* __restrict__ out) {
  extern __shared__ char smem[];
  unsigned short* Hs = (unsigned short*)smem;   // 6 slots x [128 rows][64 k] bf16, swizzled
  char* xsb = smem + 98304;                     // 2 x [128 rows][64 d] bf16, swizzled
  char* w1b = smem + 131072;                    // 2 x [64 kcol][64 d] bf16, swizzled (pre-packed)

  int bid = (int)blockIdx.x;
  // XCD-chunked swizzle: XCD g gets 112 consecutive nids; t innermost so the 7
  // target-blocks of one row-block share x[*][rows] in that XCD's L2.
  int nid = (bid & 7) * 112 + (bid >> 3);       // 896 = 8*112
  int t = nid % NH, rb = nid / NH;
  int row0 = rb * 128;

  int tid = (int)threadIdx.x;
  int wid = tid >> 6, lane = tid & 63, l16 = lane & 15, l4 = lane >> 4;

  // active-source list, 3 bits per entry (avoids runtime-indexed array -> scratch)
  unsigned spack = 0; int nact = 0;
  for (int s = 0; s < NH; ++s) {
    if (s == t) continue;
    if (fabsf(M[s * NH + t]) > THRG) { spack |= (unsigned)s << (3 * nact); ++nact; }
  }

  const f32x4 zero = {0.f, 0.f, 0.f, 0.f};

  // ================= Phase A =================
  // Wave grid 2x4 over H tile [kcol 64][row 128]: wave = 32 kcol x 32 rows.
  int mh = wid >> 2, qr = wid & 3;
  int srow = tid >> 2, ssub = tid & 3;          // x staging: 512 thr cover 128 rows x 64 d

  f32x4 accA[2][2];
#pragma unroll
  for (int mm = 0; mm < 2; ++mm)
#pragma unroll
    for (int nn = 0; nn < 2; ++nn) accA[mm][nn] = zero;

  f32x4 xr0, xr1, xr2, xr3;                     // in-flight x chunk (16 f32/thread)

  auto STAGE = [&](int s, int kc, int p) {
    // W1 chunk: async copy 8 KB (pre-swizzled source, linear dest)
    const char* wsrc = (const char*)(W1P + ((size_t)(s * NH + t) * 12 + kc) * 4096);
    gload_lds16(wsrc + tid * 16, w1b + p * 8192 + (wid << 10));
    // x chunk: 64 B/thread into registers (converted+written after this step's MFMA)
    const float* gp = x + ((size_t)s * NROW + row0 + srow) * DD + kc * 64 + ssub * 16;
    xr0 = *(const f32x4*)gp;       xr1 = *(const f32x4*)(gp + 4);
    xr2 = *(const f32x4*)(gp + 8); xr3 = *(const f32x4*)(gp + 12);
  };

  auto WRITE = [&](int p) {                     // f32 -> bf16 (compiler emits cvt_pk), swizzled
    bf16x8 lo, hi;
    lo[0] = (__bf16)xr0[0]; lo[1] = (__bf16)xr0[1]; lo[2] = (__bf16)xr0[2]; lo[3] = (__bf16)xr0[3];
    lo[4] = (__bf16)xr1[0]; lo[5] = (__bf16)xr1[1]; lo[6] = (__bf16)xr1[2]; lo[7] = (__bf16)xr1[3];
    hi[0] = (__bf16)xr2[0]; hi[1] = (__bf16)xr2[1]; hi[2] = (__bf16)xr2[2]; hi[3] = (__bf16)xr2[3];
    hi[4] = (__bf16)xr3[0]; hi[5] = (__bf16)xr3[1]; hi[6] = (__bf16)xr3[2]; hi[7] = (__bf16)xr3[3];
    char* base = xsb + p * 16384;
    int b0 = srow * 128 + ssub * 32, sw = (srow & 7) << 4;
    *(bf16x8*)(base + (b0 ^ sw)) = lo;
    *(bf16x8*)(base + ((b0 + 16) ^ sw)) = hi;
  };

  auto COMPUTE = [&](int p) {
    const char* xc = xsb + p * 16384;
    const char* wc = w1b + p * 8192;
    V8 af[2][2], bfr[2][2];
#pragma unroll
    for (int mm = 0; mm < 2; ++mm)
#pragma unroll
      for (int k2 = 0; k2 < 2; ++k2) {
        int rl = mh * 32 + mm * 16 + l16;
        af[mm][k2].s = *(const short8v*)(wc + ((rl * 128 + k2 * 64 + l4 * 16) ^ ((rl & 7) << 4)));
      }
#pragma unroll
    for (int nn = 0; nn < 2; ++nn)
#pragma unroll
      for (int k2 = 0; k2 < 2; ++k2) {
        int xrow = qr * 32 + nn * 16 + l16;
        bfr[nn][k2].s = *(const short8v*)(xc + ((xrow * 128 + k2 * 64 + l4 * 16) ^ ((xrow & 7) << 4)));
      }
#pragma unroll
    for (int k2 = 0; k2 < 2; ++k2)
#pragma unroll
      for (int mm = 0; mm < 2; ++mm)
#pragma unroll
        for (int nn = 0; nn < 2; ++nn)
          accA[mm][nn] = __builtin_amdgcn_mfma_f32_16x16x32_bf16(af[mm][k2].b, bfr[nn][k2].b,
                                                                 accA[mm][nn], 0, 0, 0);
  };

  auto EPIA = [&](int s, int slot) {            // +b1, gelu, bf16 -> Hs[slot], reset acc
    int pr = s * NH + t;
    char* hb = (char*)(Hs + slot * 8192);
#pragma unroll
    for (int mm = 0; mm < 2; ++mm) {
      f32x4 bv = *(const f32x4*)(b1 + (size_t)pr * KK + mh * 32 + mm * 16 + l4 * 4);
#pragma unroll
      for (int nn = 0; nn < 2; ++nn) {
        union { short4v s4; __bf16 b4[4]; } o;
#pragma unroll
        for (int r = 0; r < 4; ++r) o.b4[r] = (__bf16)gelu_t(accA[mm][nn][r] + bv[r]);
        int xrow = qr * 32 + nn * 16 + l16;
        *(short4v*)(hb + ((xrow * 128 + mh * 64 + mm * 32 + l4 * 8) ^ ((xrow & 7) << 4))) = o.s4;
        accA[mm][nn] = zero;
      }
    }
  };

  if (nact > 0) {
    const int NSTEP = nact * 12;
    STAGE(spack & 7, 0, 0);
    WRITE(0);
    __syncthreads();
    int si = 0, kc = 0;
    for (int step = 0; step < NSTEP; ++step) {
      int p = step & 1;
      int kn = kc + 1, sn = si;
      if (kn == 12) { kn = 0; sn = si + 1; }
      bool more = (step + 1 < NSTEP);
      if (more) STAGE((spack >> (3 * sn)) & 7, kn, p ^ 1);   // prefetch next chunk
      COMPUTE(p);
      if (more) WRITE(p ^ 1);
      if (kc == 11) EPIA((spack >> (3 * si)) & 7, si);
      __syncthreads();
      kc = kn; si = sn;
    }
  }

  // ================= Phase B =================
  // Wave grid 2x4 over out tile [row 128][col 256 per cb]: wave = 64 rows x 64 cols.
  // Swapped operands (A = W2 cols) so D-frag regs run along columns -> f32x4 stores.
  int wr = wid & 1, wc = wid >> 1;
#pragma unroll 1
  for (int cb = 0; cb < 3; ++cb) {
    int colb = cb * 256 + wc * 64;
    f32x4 acc[4][4];
#pragma unroll
    for (int m = 0; m < 4; ++m)
#pragma unroll
      for (int n = 0; n < 4; ++n) acc[m][n] = zero;

    for (int i = 0; i < nact; ++i) {
      int s = (spack >> (3 * i)) & 7;
      const char* wp = (const char*)(W2P + ((size_t)(t * NH + s) * DD + colb) * KK);
      const char* hb = (const char*)(Hs + i * 8192);
      V8 af[4][2], bfr[4][2];
#pragma unroll
      for (int m = 0; m < 4; ++m)
#pragma unroll
        for (int k2 = 0; k2 < 2; ++k2)
          af[m][k2].s = *(const short8v*)(wp + (m * 16 + l16) * 128 + k2 * 64 + l4 * 16);
#pragma unroll
      for (int n = 0; n < 4; ++n)
#pragma unroll
        for (int k2 = 0; k2 < 2; ++k2) {
          int xrow = wr * 64 + n * 16 + l16;
          bfr[n][k2].s = *(const short8v*)(hb + ((xrow * 128 + k2 * 64 + l4 * 16) ^ ((xrow & 7) << 4)));
        }
#pragma unroll
      for (int k2 = 0; k2 < 2; ++k2)
#pragma unroll
        for (int m = 0; m < 4; ++m)
#pragma unroll
          for (int n = 0; n < 4; ++n)
            acc[m][n] = __builtin_amdgcn_mfma_f32_16x16x32_bf16(af[m][k2].b, bfr[n][k2].b,
                                                                acc[m][n], 0, 0, 0);
    }

    // epilogue: + x residual (exact f32) + b2sum; coalesced f32x4 stores
#pragma unroll
    for (int m = 0; m < 4; ++m) {
      int col = colb + m * 16 + l4 * 4;
      f32x4 bv = *(const f32x4*)(b2sum + (size_t)t * DD + col);
#pragma unroll
      for (int n = 0; n < 4; ++n) {
        int row = row0 + wr * 64 + n * 16 + l16;
        size_t off = ((size_t)t * NROW + row) * DD + col;
        f32x4 xv = *(const f32x4*)(x + off);
        f32x4 ov;
#pragma unroll
        for (int r = 0; r < 4; ++r) ov[r] = acc[m][n][r] + xv[r] + bv[r];
        *(f32x4*)(out + off) = ov;
      }
    }
  }
}

extern "C" void kernel_launch(void* const* d_in, const int* in_sizes, int n_in,
                              void* d_out, int out_size, void* d_ws, size_t ws_size,
                              hipStream_t stream) {
  const float* x  = (const float*)d_in[0];
  const float* M  = (const float*)d_in[1];
  const float* W1 = (const float*)d_in[2];
  const float* b1 = (const float*)d_in[3];
  const float* W2 = (const float*)d_in[4];
  const float* b2 = (const float*)d_in[5];
  float* out = (float*)d_out;

  char* ws = (char*)d_ws;
  unsigned short* W1P = (unsigned short*)ws;                         // 4,816,896 B
  unsigned short* W2P = (unsigned short*)(ws + 4816896);             // 4,816,896 B
  float* b2sum        = (float*)(ws + 9633792);                      // 21,504 B

  // allow 144 KB dynamic LDS (idempotent; not a stream op, graph-capture safe)
  static bool attr_set = false;
  if (!attr_set) {
    (void)hipFuncSetAttribute((const void*)chiF,
                              hipFuncAttributeMaxDynamicSharedMemorySize, 147456);
    attr_set = true;
  }

  prep_w1<<<dim3(49), dim3(256), 0, stream>>>(W1, W1P);
  prep_w2<<<dim3(49), dim3(256), 0, stream>>>(M, W2, W2P);
  prep_b2<<<dim3((NH * DD + 255) / 256), dim3(256), 0, stream>>>(M, b2, b2sum);
  chiF<<<dim3(896), dim3(512), 147456, stream>>>(x, M, W1P, b1, W2P, b2sum, out);
}

// Round 2
// 574.559 us; speedup vs baseline: 1.1976x; 1.1976x over previous
//
#include <hip/hip_runtime.h>
#include <math.h>

// Problem constants
#define NH   7        // hazards
#define NROW 16384    // B*S = 8*2048
#define DD   768      // hidden dim
#define KK   64       // bottleneck dim
#define THRG 0.05f

typedef float  f32x4   __attribute__((ext_vector_type(4)));
typedef __bf16 bf16x8  __attribute__((ext_vector_type(8)));
typedef short  short8v __attribute__((ext_vector_type(8)));
typedef short  short4v __attribute__((ext_vector_type(4)));

union V8 { short8v s; bf16x8 b; };

__device__ __forceinline__ unsigned short f2bf(float f) {
  unsigned u = __float_as_uint(f);
  u = (u + 0x7FFFu + ((u >> 16) & 1u)) >> 16;   // round-to-nearest-even
  return (unsigned short)u;
}

__device__ __forceinline__ float gate_of(const float* __restrict__ M, int s, int t) {
  float m = M[s * NH + t];
  return (s != t && fabsf(m) > THRG) ? m : 0.0f;
}

__device__ __forceinline__ float gelu_t(float v) {
  float u = 0.7978845608028654f * (v + 0.044715f * v * v * v);
  return v / (1.0f + __expf(-2.0f * u));   // v * sigmoid(2u)
}

// async 16B global -> LDS copy; lds ptr must be the WAVE-uniform base (HW adds lane*16)
__device__ __forceinline__ void gload_lds16(const void* g, void* l) {
  __builtin_amdgcn_global_load_lds(
      (const __attribute__((address_space(1))) unsigned int*)g,
      (__attribute__((address_space(3))) unsigned int*)l, 16, 0, 0);
}

// ---- prep: W1 [s][t][d][k] f32 -> W1P [pr][kc][kcol(64)][dl(64)] bf16,
// PRE-SWIZZLED (inverse of the LDS read XOR) so global_load_lds can copy linearly.
__global__ void prep_w1(const float* __restrict__ W1, unsigned short* __restrict__ W1P) {
  int pr = blockIdx.x;                       // pr = s*7+t
  const float* src = W1 + (size_t)pr * DD * KK;
  unsigned short* dst = W1P + (size_t)pr * 12 * 4096;
  for (int idx = threadIdx.x; idx < 12 * 4096; idx += blockDim.x) {
    int kc = idx >> 12, rem = idx & 4095;
    int kcol = rem >> 6, dl = rem & 63;
    int dl_log = dl ^ ((kcol & 7) << 3);     // elem-space inverse of byte XOR ((row&7)<<4)
    dst[idx] = f2bf(src[(size_t)(kc * 64 + dl_log) * KK + kcol]);
  }
}

// ---- prep: W2 [s][t][k][d] f32 -> W2P [t][s][d(768)][k(64)] bf16, gate folded.
// Read directly from global (L2-hot) as MFMA A-fragments; no swizzle needed.
__global__ void prep_w2(const float* __restrict__ M, const float* __restrict__ W2,
                        unsigned short* __restrict__ W2P) {
  int st = blockIdx.x;                       // st = s*7+t
  int s = st / NH, t = st % NH;
  float g = gate_of(M, s, t);
  const float* src = W2 + (size_t)st * KK * DD;
  unsigned short* dst = W2P + (size_t)(t * NH + s) * DD * KK;
  for (int idx = threadIdx.x; idx < DD * KK; idx += blockDim.x) {
    int d = idx >> 6, k = idx & 63;
    dst[idx] = f2bf(g * src[(size_t)k * DD + d]);
  }
}

// ---- prep: b2sum[t][d] = sum_s gate(s,t) * b2[s][t][d]
__global__ void prep_b2(const float* __restrict__ M, const float* __restrict__ b2,
                        float* __restrict__ b2sum) {
  int idx = blockIdx.x * blockDim.x + threadIdx.x;
  if (idx >= NH * DD) return;
  int t = idx / DD, d = idx % DD;
  float acc = 0.f;
  for (int s = 0; s < NH; ++s)
    acc += gate_of(M, s, t) * b2[(size_t)(s * NH + t) * DD + d];
  b2sum[idx] = acc;
}

// ---- Phase A: H[pr][rb] (blocked 16KB, XOR-swizzled) = gelu(x[s] W1[s,t] + b1), bf16.
// 2-phase pipeline: one barrier per kc step; W1 via global_load_lds (pre-swizzled
// source, linear dest); x prefetched to regs at step start, converted + ds_written
// after the MFMAs so HBM latency hides under compute (T14 split).
__global__ __launch_bounds__(256, 3)
void chiA(const float* __restrict__ x, const float* __restrict__ M,
          const unsigned short* __restrict__ W1P, const float* __restrict__ b1,
          unsigned short* __restrict__ H) {
  __shared__ __align__(16) unsigned short xs[2][128 * 64];   // 2 x 16 KB, swizzled [row][d]
  __shared__ __align__(16) unsigned short w1s[2][64 * 64];   // 2 x  8 KB, swizzled [kcol][d]

  int bid = (int)blockIdx.x;
  int nid = (bid & 7) * 784 + (bid >> 3);   // 6272 = 8*784; t innermost -> L2 reuse of x chunk
  int rb = nid / 49, pr = nid % 49;
  int s = pr / NH, t = pr % NH;
  if (gate_of(M, s, t) == 0.0f) return;
  int row0 = rb * 128;

  int tid = (int)threadIdx.x;
  int wid = tid >> 6, lane = tid & 63, l16 = lane & 15, l4 = lane >> 4;

  const float* xb = x + ((size_t)s * NROW + row0) * DD;
  const char* w1b = (const char*)(W1P + (size_t)pr * 12 * 4096);

  const f32x4 zero = {0.f, 0.f, 0.f, 0.f};
  f32x4 acc[4][2];
#pragma unroll
  for (int m = 0; m < 4; ++m)
#pragma unroll
    for (int n = 0; n < 2; ++n) acc[m][n] = zero;

  int xro = tid >> 3;                 // row within 32-row quarter
  int xco = (tid & 7) * 8;            // f32 col within 64
  int sw = (xro & 7) << 4;            // swizzle (row&7) — r*32 doesn't change row&7

  f32x4 xr[8];                        // in-flight x chunk: 32 f32/thread

  auto STAGE = [&](int kc, int p) {
    const char* wsrc = w1b + (size_t)kc * 8192;
    char* wdst = (char*)w1s[p] + (wid << 10);
#pragma unroll
    for (int r = 0; r < 2; ++r)
      gload_lds16(wsrc + r * 4096 + tid * 16, wdst + r * 4096);
#pragma unroll
    for (int r = 0; r < 4; ++r) {
      const float* gp = xb + (size_t)(r * 32 + xro) * DD + kc * 64 + xco;
      xr[2 * r]     = *(const f32x4*)gp;
      xr[2 * r + 1] = *(const f32x4*)(gp + 4);
    }
  };

  auto WRITE = [&](int p) {           // f32 -> bf16 (cvt_pk), swizzled ds_write_b128
#pragma unroll
    for (int r = 0; r < 4; ++r) {
      bf16x8 v;
      v[0] = (__bf16)xr[2*r][0]; v[1] = (__bf16)xr[2*r][1];
      v[2] = (__bf16)xr[2*r][2]; v[3] = (__bf16)xr[2*r][3];
      v[4] = (__bf16)xr[2*r+1][0]; v[5] = (__bf16)xr[2*r+1][1];
      v[6] = (__bf16)xr[2*r+1][2]; v[7] = (__bf16)xr[2*r+1][3];
      int L = r * 4096 + tid * 16;
      *(bf16x8*)((char*)xs[p] + (L ^ sw)) = v;
    }
  };

  auto COMPUTE = [&](int p) {
    V8 af[4][2], bf2[2][2];
#pragma unroll
    for (int mm = 0; mm < 4; ++mm)
#pragma unroll
      for (int k2 = 0; k2 < 2; ++k2) {
        int rl = mm * 16 + l16;
        af[mm][k2].s = *(const short8v*)((const char*)w1s[p] +
                         ((rl * 128 + k2 * 64 + l4 * 16) ^ ((rl & 7) << 4)));
      }
#pragma unroll
    for (int nn = 0; nn < 2; ++nn)
#pragma unroll
      for (int k2 = 0; k2 < 2; ++k2) {
        int rl = wid * 32 + nn * 16 + l16;
        bf2[nn][k2].s = *(const short8v*)((const char*)xs[p] +
                          ((rl * 128 + k2 * 64 + l4 * 16) ^ ((rl & 7) << 4)));
      }
#pragma unroll
    for (int k2 = 0; k2 < 2; ++k2)
#pragma unroll
      for (int mm = 0; mm < 4; ++mm)
#pragma unroll
        for (int nn = 0; nn < 2; ++nn)
          acc[mm][nn] = __builtin_amdgcn_mfma_f32_16x16x32_bf16(af[mm][k2].b, bf2[nn][k2].b,
                                                                acc[mm][nn], 0, 0, 0);
  };

  STAGE(0, 0);
  WRITE(0);
  __syncthreads();                    // drains gload W1(0) + ds_writes
  int p = 0;
  for (int kc = 0; kc < 12; ++kc) {
    bool more = (kc + 1 < 12);
    if (more) STAGE(kc + 1, p ^ 1);   // issue next-chunk loads first
    COMPUTE(p);
    if (more) WRITE(p ^ 1);           // x latency hidden under MFMAs
    __syncthreads();
    p ^= 1;
  }

  // epilogue: +b1, gelu, store bf16 into blocked PRE-SWIZZLED H (for chiB's gload_lds)
  unsigned short* Hb = H + ((size_t)pr * 128 + rb) * 8192;
#pragma unroll
  for (int mm = 0; mm < 4; ++mm) {
    f32x4 bv = *(const f32x4*)(b1 + (size_t)pr * KK + mm * 16 + l4 * 4);
#pragma unroll
    for (int nn = 0; nn < 2; ++nn) {
      union { short4v s4; __bf16 b4[4]; } o;
#pragma unroll
      for (int r = 0; r < 4; ++r) o.b4[r] = (__bf16)gelu_t(acc[mm][nn][r] + bv[r]);
      int rl = wid * 32 + nn * 16 + l16;
      *(short4v*)((char*)Hb + ((rl * 128 + mm * 32 + l4 * 8) ^ ((rl & 7) << 4))) = o.s4;
    }
  }
}

// ---- Phase B: out[t] = x[t] + sum_s H[s,t](128xK) * W2P[t,s](Kx128) + b2sum[t]
// H staged via global_load_lds (already swizzled), double-buffered over the s-loop,
// one barrier per source. W2 A-frags direct from L2-resident W2P. Swapped operands
// so D-frag regs run along out-columns -> coalesced f32x4 stores.
__global__ __launch_bounds__(256, 3)
void chiB(const unsigned short* __restrict__ H, const float* __restrict__ x,
          const float* __restrict__ M, const unsigned short* __restrict__ W2P,
          const float* __restrict__ b2sum, float* __restrict__ out) {
  __shared__ __align__(16) unsigned short hs[2][128 * 64];   // 2 x 16 KB, swizzled [row][k]

  int bid = (int)blockIdx.x;
  int nid = (bid & 7) * 672 + (bid >> 3);   // 5376 = 8*672; nb innermost -> L2 reuse of H chunk
  int nb = nid % 6, rem = nid / 6;
  int rb = rem % 128, t = rem / 128;
  int row0 = rb * 128, col0 = nb * 128;

  int tid = (int)threadIdx.x;
  int wid = tid >> 6, lane = tid & 63, l16 = lane & 15, l4 = lane >> 4;
  int wr = wid & 1, wc = wid >> 1;          // wave = 64 rows x 64 cols of the 128x128 tile

  // active-source list, 3 bits per entry
  unsigned spack = 0; int nact = 0;
  for (int s = 0; s < NH; ++s) {
    if (s == t) continue;
    if (fabsf(M[s * NH + t]) > THRG) { spack |= (unsigned)s << (3 * nact); ++nact; }
  }

  const f32x4 zero = {0.f, 0.f, 0.f, 0.f};
  f32x4 acc[4][4];
#pragma unroll
  for (int m = 0; m < 4; ++m)
#pragma unroll
    for (int n = 0; n < 4; ++n) acc[m][n] = zero;

  auto GLOADH = [&](int s, int p) {
    const char* src = (const char*)H + ((size_t)(s * NH + t) * 128 + rb) * 16384;
    char* dst = (char*)hs[p] + (wid << 10);
#pragma unroll
    for (int r = 0; r < 4; ++r)
      gload_lds16(src + r * 4096 + tid * 16, dst + r * 4096);
  };

  if (nact > 0) {
    GLOADH(spack & 7, 0);
    int p = 0;
    for (int i = 0; i < nact; ++i) {
      __syncthreads();                         // vmcnt(0) drain: hs[p] ready
      if (i + 1 < nact) GLOADH((spack >> (3 * (i + 1))) & 7, p ^ 1);
      int s = (spack >> (3 * i)) & 7;
      const char* wp = (const char*)(W2P + ((size_t)(t * NH + s) * DD + col0 + wc * 64) * KK);
      V8 af[4][2], bfr[4][2];
#pragma unroll
      for (int m = 0; m < 4; ++m)
#pragma unroll
        for (int k2 = 0; k2 < 2; ++k2)
          af[m][k2].s = *(const short8v*)(wp + (((m * 16 + l16) * 64 + k2 * 32 + l4 * 8) * 2));
#pragma unroll
      for (int n = 0; n < 4; ++n)
#pragma unroll
        for (int k2 = 0; k2 < 2; ++k2) {
          int rl = wr * 64 + n * 16 + l16;
          bfr[n][k2].s = *(const short8v*)((const char*)hs[p] +
                           ((rl * 128 + k2 * 64 + l4 * 16) ^ ((rl & 7) << 4)));
        }
#pragma unroll
      for (int k2 = 0; k2 < 2; ++k2)
#pragma unroll
        for (int m = 0; m < 4; ++m)
#pragma unroll
          for (int n = 0; n < 4; ++n)
            acc[m][n] = __builtin_amdgcn_mfma_f32_16x16x32_bf16(af[m][k2].b, bfr[n][k2].b,
                                                                acc[m][n], 0, 0, 0);
      p ^= 1;
    }
  }

  // epilogue: + x residual (exact f32) + b2sum; coalesced f32x4 stores along cols
#pragma unroll
  for (int m = 0; m < 4; ++m) {
    int col = col0 + wc * 64 + m * 16 + l4 * 4;
    f32x4 bv = *(const f32x4*)(b2sum + (size_t)t * DD + col);
#pragma unroll
    for (int n = 0; n < 4; ++n) {
      int row = row0 + wr * 64 + n * 16 + l16;
      size_t off = ((size_t)t * NROW + row) * DD + col;
      f32x4 xv = *(const f32x4*)(x + off);
      f32x4 ov;
#pragma unroll
      for (int r = 0; r < 4; ++r) ov[r] = acc[m][n][r] + xv[r] + bv[r];
      *(f32x4*)(out + off) = ov;
    }
  }
}

extern "C" void kernel_launch(void* const* d_in, const int* in_sizes, int n_in,
                              void* d_out, int out_size, void* d_ws, size_t ws_size,
                              hipStream_t stream) {
  const float* x  = (const float*)d_in[0];
  const float* M  = (const float*)d_in[1];
  const float* W1 = (const float*)d_in[2];
  const float* b1 = (const float*)d_in[3];
  const float* W2 = (const float*)d_in[4];
  const float* b2 = (const float*)d_in[5];
  float* out = (float*)d_out;

  char* ws = (char*)d_ws;
  unsigned short* W1P = (unsigned short*)ws;                         // 4,816,896 B
  unsigned short* W2P = (unsigned short*)(ws + 4816896);             // 4,816,896 B
  float* b2sum        = (float*)(ws + 9633792);                      // 21,504 B
  unsigned short* H   = (unsigned short*)(ws + 9655296);             // 102,760,448 B (blocked)

  prep_w1<<<dim3(49), dim3(256), 0, stream>>>(W1, W1P);
  prep_w2<<<dim3(49), dim3(256), 0, stream>>>(M, W2, W2P);
  prep_b2<<<dim3((NH * DD + 255) / 256), dim3(256), 0, stream>>>(M, b2, b2sum);
  chiA<<<dim3(128 * 49), dim3(256), 0, stream>>>(x, M, W1P, b1, H);
  chiB<<<dim3(NH * 128 * 6), dim3(256), 0, stream>>>(H, x, M, W2P, b2sum, out);
}